// Round 2
// baseline (2529.195 us; speedup 1.0000x reference)
//
#include <hip/hip_runtime.h>
#include <hip/hip_bf16.h>

#define NN 6144
#define DD 64
#define NL 3
#define KK 24
#define RT 32   // rows per block (adj kernel)
#define CT 64   // cols per tile
#define NT (NN / CT)

// Bit-level emulation of XLA CPU f32 tanh, FMA variant (llvm_ir::EmitFastTanh
// with_fma=true / MLIR polynomial-approximation / Eigen ptanh AVX2+):
// clamp to +-7.99881172180175781, Horner via fused fma, |x|<4e-4 -> x.
__device__ __forceinline__ float tanh_xla(float x) {
  const float kClamp = 7.99881172180175781f;
  float xc = fminf(fmaxf(x, -kClamp), kClamp);
  float x2 = xc * xc;
  float p = -2.76076847742355e-16f;
  p = fmaf(p, x2, 2.00018790482477e-13f);
  p = fmaf(p, x2, -8.60467152213735e-11f);
  p = fmaf(p, x2, 5.12229709037114e-08f);
  p = fmaf(p, x2, 1.48572235717979e-05f);
  p = fmaf(p, x2, 6.37261928875436e-04f);
  p = fmaf(p, x2, 4.89352455891786e-03f);
  p = xc * p;
  float q = 1.19825839466702e-06f;
  q = fmaf(q, x2, 1.18534705686654e-04f);
  q = fmaf(q, x2, 2.26843463243900e-03f);
  q = fmaf(q, x2, 4.89352518554385e-03f);
  float r = p / q;   // default hipcc: IEEE correctly-rounded f32 div (matches CPU divss)
  return (fabsf(x) < 0.0004f) ? x : r;
}

// Kernel A: 3-layer tanh MLP chains for nodevec1/nodevec2. Thread = one row.
// Dot products are sequential-k fmaf chains (matches Eigen gebp accumulation).
// Block 0 additionally computes M_tv = global max of the rounded tanh rational
// (sampled on [7,8], plateau widths there >= 0.018 >> step 4e-5).
__global__ __launch_bounds__(256) void mlp_kernel(
    const int* __restrict__ idx, const float* __restrict__ scale_set,
    const float* __restrict__ emb1, const float* __restrict__ emb2,
    const float* __restrict__ W1, const float* __restrict__ b1,
    const float* __restrict__ W2, const float* __restrict__ b2,
    float* __restrict__ v1s, float* __restrict__ v2s, float* __restrict__ mtv) {
  __shared__ float Wsh1[DD * DD];
  __shared__ float Wsh2[DD * DD];
  __shared__ float bsh1[DD];
  __shared__ float bsh2[DD];
  const int t = threadIdx.x;
  const int row = blockIdx.x * 256 + t;

  float u1[DD], u2[DD];

  for (int l = 0; l < NL; ++l) {
    __syncthreads();  // protect previous layer's LDS weights before overwrite
    for (int i = t; i < (DD * DD) / 4; i += 256) {
      ((float4*)Wsh1)[i] = ((const float4*)(W1 + l * DD * DD))[i];
      ((float4*)Wsh2)[i] = ((const float4*)(W2 + l * DD * DD))[i];
    }
    if (t < DD) { bsh1[t] = b1[l * DD + t]; bsh2[t] = b2[l * DD + t]; }
    __syncthreads();

    const float s = scale_set[l];
    const float* src1;
    const float* src2;
    if (l == 0) {
      int g = idx[row];
      src1 = emb1 + (size_t)g * DD;
      src2 = emb2 + (size_t)g * DD;
    } else {
      src1 = v1s + ((size_t)(l - 1) * NN + row) * DD;
      src2 = v2s + ((size_t)(l - 1) * NN + row) * DD;
    }
#pragma unroll
    for (int k = 0; k < DD; ++k) {
      u1[k] = src1[k] * s;  // materialized (nodevec * scale), single rounding
      u2[k] = src2[k] * s;
    }
    float* o1 = v1s + ((size_t)l * NN + row) * DD;
    float* o2 = v2s + ((size_t)l * NN + row) * DD;
    for (int j = 0; j < DD; ++j) {
      float a1 = 0.0f, a2 = 0.0f;
#pragma unroll
      for (int k = 0; k < DD; ++k) {
        a1 = fmaf(u1[k], Wsh1[j * DD + k], a1);
        a2 = fmaf(u2[k], Wsh2[j * DD + k], a2);
      }
      float z1 = 3.0f * (a1 + bsh1[j]);
      float z2 = 3.0f * (a2 + bsh2[j]);
      o1[j] = tanh_xla(z1);
      o2[j] = tanh_xla(z2);
    }
  }

  // Compute the exact global max of the rounded tanh approximation.
  if (blockIdx.x == 0) {
    __syncthreads();
    float lm = 0.0f;
    for (int i = 0; i < 96; ++i) {
      float x = 7.0f + (float)(t * 96 + i) * (1.0f / 24576.0f);
      lm = fmaxf(lm, tanh_xla(x));
    }
    Wsh1[t] = lm;
    __syncthreads();
    if (t == 0) {
      float m = 0.0f;
      for (int i = 0; i < 256; ++i) m = fmaxf(m, Wsh1[i]);
      mtv[0] = m;
    }
  }
}

// Kernel B: per (layer, 32-row tile): zero-fill output slab, stream all column
// tiles, compute exact f32 a = v1.v2c - v2.v1c (sequential-k fmaf chains),
// maintain stable top-24 per row (value desc, index asc), scatter at end.
__global__ __launch_bounds__(128) void adj_kernel(
    const float* __restrict__ v1s, const float* __restrict__ v2s,
    const float* __restrict__ mtv, float* __restrict__ out) {
  __shared__ float R1t[DD][RT];      // [k][row]  row-side v1
  __shared__ float R2t[DD][RT];
  __shared__ float C1t[DD][CT];      // [k][col]  col-side v1
  __shared__ float C2t[DD][CT];
  __shared__ float A[RT][CT + 1];    // a-tile, padded
  __shared__ float kv[KK][RT];       // topk values, slot 0 = weakest
  __shared__ int   ki[KK][RT];       // corresponding column index
  // total LDS: 16K + 32K + 8.3K + 3K + 3K = 63.6 KiB (< 64 KiB)

  const int l = blockIdx.y;
  const int r0 = blockIdx.x * RT;
  const int t = threadIdx.x;
  const float* v1 = v1s + (size_t)l * NN * DD;
  const float* v2 = v2s + (size_t)l * NN * DD;
  float* o = out + (size_t)l * NN * NN;
  const float Mtv = mtv[0];

  // Zero-fill this block's 32-row output slab (coalesced float4 stores).
  {
    float4 z = make_float4(0.f, 0.f, 0.f, 0.f);
    float4* dst = (float4*)(o + (size_t)r0 * NN);
    for (int i = t; i < RT * NN / 4; i += 128) dst[i] = z;
  }

  // Stage row-side vectors transposed: R1t[k][r] = v1[r0+r][k].
  {
    int r = t >> 2;              // 0..31
    int k0 = (t & 3) * 16;       // 0,16,32,48
#pragma unroll
    for (int i = 0; i < 4; ++i) {
      float4 g1 = *(const float4*)(v1 + (size_t)(r0 + r) * DD + k0 + i * 4);
      float4 g2 = *(const float4*)(v2 + (size_t)(r0 + r) * DD + k0 + i * 4);
      int kk = k0 + i * 4;
      R1t[kk + 0][r] = g1.x; R1t[kk + 1][r] = g1.y; R1t[kk + 2][r] = g1.z; R1t[kk + 3][r] = g1.w;
      R2t[kk + 0][r] = g2.x; R2t[kk + 1][r] = g2.y; R2t[kk + 2][r] = g2.z; R2t[kk + 3][r] = g2.w;
    }
  }
  if (t < RT) {
#pragma unroll
    for (int j = 0; j < KK; ++j) { kv[j][t] = 0.0f; ki[j][t] = 0; }
  }
  float kv0 = 0.0f;
  bool sat = false;  // row's 24 slots all at the tanh global max -> frozen

  const int ty = t >> 4;   // 0..7 -> 4 rows each
  const int tx = t & 15;   // 0..15 -> 4 cols each

  for (int ct = 0; ct <= NT; ++ct) {
    // Stage col tile ct (all threads).
    if (ct < NT) {
      int c = t >> 1;
      int kh = (t & 1) * 32;
      const float* g1 = v1 + (size_t)(ct * CT + c) * DD + kh;
      const float* g2 = v2 + (size_t)(ct * CT + c) * DD + kh;
#pragma unroll
      for (int i = 0; i < 8; ++i) {
        float4 a4 = *(const float4*)(g1 + i * 4);
        float4 b4 = *(const float4*)(g2 + i * 4);
        int kk = kh + i * 4;
        C1t[kk + 0][c] = a4.x; C1t[kk + 1][c] = a4.y; C1t[kk + 2][c] = a4.z; C1t[kk + 3][c] = a4.w;
        C2t[kk + 0][c] = b4.x; C2t[kk + 1][c] = b4.y; C2t[kk + 2][c] = b4.z; C2t[kk + 3][c] = b4.w;
      }
    }
    // Scan previous tile's a-values (lane = row). Strict '>' + ascending col
    // order reproduces jax.lax.top_k's lower-index tie-break. Full tanh eval
    // on every positive entry (no raw-a shortcut: rounded rational may be
    // locally non-monotone); exact freeze once all 24 slots hit the global max.
    if (ct > 0 && t < RT && !sat) {
      int cb = (ct - 1) * CT;
      for (int c = 0; c < CT; ++c) {
        float a = A[t][c];
        if (a > 0.0f) {
          float tv = tanh_xla(3.0f * a);  // > 0, relu is a no-op here
          if (tv > kv0) {
            int p = 1;
            while (p < KK && kv[p][t] < tv) {
              kv[p - 1][t] = kv[p][t]; ki[p - 1][t] = ki[p][t];
              ++p;
            }
            kv[p - 1][t] = tv; ki[p - 1][t] = cb + c;
            kv0 = kv[0][t];
          }
        }
      }
      sat = (kv0 >= Mtv);
    }
    __syncthreads();
    // Compute tile ct: 4x4 per-thread register tile, two sequential-k fmaf
    // chains per entry (bit-matches Eigen's per-element accumulation).
    if (ct < NT) {
      float acc1[4][4] = {{0.f}}, acc2[4][4] = {{0.f}};
#pragma unroll 8
      for (int k = 0; k < DD; ++k) {
        float4 rv1 = *(const float4*)&R1t[k][4 * ty];
        float4 rv2 = *(const float4*)&R2t[k][4 * ty];
        float4 cv1 = *(const float4*)&C1t[k][4 * tx];
        float4 cv2 = *(const float4*)&C2t[k][4 * tx];
        const float* r1 = (const float*)&rv1;
        const float* r2 = (const float*)&rv2;
        const float* c1 = (const float*)&cv1;
        const float* c2 = (const float*)&cv2;
#pragma unroll
        for (int i = 0; i < 4; ++i)
#pragma unroll
          for (int j = 0; j < 4; ++j) {
            acc1[i][j] = fmaf(r1[i], c2[j], acc1[i][j]);  // v1_r . v2_c
            acc2[i][j] = fmaf(r2[i], c1[j], acc2[i][j]);  // v2_r . v1_c
          }
      }
#pragma unroll
      for (int i = 0; i < 4; ++i)
#pragma unroll
        for (int j = 0; j < 4; ++j)
          A[4 * ty + i][4 * tx + j] = acc1[i][j] - acc2[i][j];
    }
    __syncthreads();
  }

  // Scatter top-24 nonzeros into the zeroed slab.
  if (t < RT) {
    float* orow = o + (size_t)(r0 + t) * NN;
#pragma unroll
    for (int j = 0; j < KK; ++j) {
      float v = kv[j][t];
      if (v > 0.0f) orow[ki[j][t]] = v;
    }
  }
}

extern "C" void kernel_launch(void* const* d_in, const int* in_sizes, int n_in,
                              void* d_out, int out_size, void* d_ws, size_t ws_size,
                              hipStream_t stream) {
  const int*   idx       = (const int*)d_in[0];
  // d_in[1] = scale_idx (unused by reference body)
  const float* scale_set = (const float*)d_in[2];
  const float* emb1      = (const float*)d_in[3];
  const float* emb2      = (const float*)d_in[4];
  const float* W1        = (const float*)d_in[5];
  const float* b1        = (const float*)d_in[6];
  const float* W2        = (const float*)d_in[7];
  const float* b2        = (const float*)d_in[8];
  float* out = (float*)d_out;

  float* v1s = (float*)d_ws;                       // [3][6144][64] f32
  float* v2s = v1s + (size_t)NL * NN * DD;         // [3][6144][64] f32
  float* mtv = v2s + (size_t)NL * NN * DD;         // [1] f32 tanh global max

  mlp_kernel<<<NN / 256, 256, 0, stream>>>(idx, scale_set, emb1, emb2, W1, b1, W2, b2, v1s, v2s, mtv);
  adj_kernel<<<dim3(NN / RT, NL), 128, 0, stream>>>(v1s, v2s, mtv, out);
}